// Round 3
// baseline (1012.848 us; speedup 1.0000x reference)
//
#include <hip/hip_runtime.h>
#include <stdint.h>

#define N_DOCS 2000000
#define DIM 20
#define SLATE 5
#define KSEL 100
#define CUT_BIN 1544   /* ord-key>>21 bin of d2 = 8.0f ; bins below => d2 < 8.0 */
#define CAPF 4096      /* per-slate filtered (bin <= b*) staged in LDS for ranking */
#define NT 256

// ws layout (bytes):
// 0      : proto f32[128]
// 512    : pn2 f32[8]
// 1024   : hist u32[SLATE][CUT_BIN]   (30,880 B)
// 32768  : cnt u32[SLATE] + overflow flag
// 65536  : cand uint2[SLATE][capN]    (capN from ws_size, <= 32768)

__device__ __forceinline__ unsigned f2ord(float f) {
    unsigned u = __float_as_uint(f);
    return (u & 0x80000000u) ? ~u : (u | 0x80000000u);
}

__device__ __forceinline__ void load20(const float* __restrict__ base, float* v) {
    const float4* p = reinterpret_cast<const float4*>(base);
#pragma unroll
    for (int k = 0; k < 5; ++k) {
        float4 q = p[k];
        v[4*k+0] = q.x; v[4*k+1] = q.y; v[4*k+2] = q.z; v[4*k+3] = q.w;
    }
}

__global__ __launch_bounds__(512) void k_proto(
        const float* __restrict__ state,
        const float* __restrict__ W0, const float* __restrict__ b0,
        const float* __restrict__ W1, const float* __restrict__ b1,
        const float* __restrict__ W2, const float* __restrict__ b2,
        float* __restrict__ proto_g, float* __restrict__ pn2_g,
        unsigned* __restrict__ hist, unsigned* __restrict__ cnt) {
    __shared__ float s_x[DIM];
    __shared__ float s_h0[256];
    __shared__ float s_h1[512];
    __shared__ float s_p[SLATE*DIM];
    int t = threadIdx.x;
    // zero histogram + counters (ws is re-poisoned 0xAA before every launch)
    for (int i = t; i < SLATE*CUT_BIN; i += 512) hist[i] = 0u;
    if (t < 8) cnt[t] = 0u;
    if (t < DIM) s_x[t] = state[t];
    __syncthreads();
    if (t < 256) {
        float a = b0[t];
#pragma unroll
        for (int d = 0; d < DIM; ++d) a += s_x[d] * W0[d*256 + t];
        s_h0[t] = a > 0.f ? a : 0.01f*a;
    }
    __syncthreads();
    if (t < 512) {
        float a = b1[t];
        for (int j = 0; j < 256; ++j) a += s_h0[j] * W1[j*512 + t];
        s_h1[t] = a > 0.f ? a : 0.01f*a;
    }
    __syncthreads();
    if (t < SLATE*DIM) {
        float a = b2[t];
        for (int j = 0; j < 512; ++j) a += s_h1[j] * W2[j*(SLATE*DIM) + t];
        float p = a > 0.f ? a : 0.01f*a;
        s_p[t] = p;
        proto_g[t] = p;
    }
    __syncthreads();
    if (t < SLATE) {
        float a = 0.f;
#pragma unroll
        for (int d = 0; d < DIM; ++d) { float p = s_p[t*DIM + d]; a += p*p; }
        pn2_g[t] = a;
    }
}

// Single streaming pass: d2 for all (slate, doc); histogram the low tail and
// collect (key, idx) for every doc with d2 < 8.0 (bin < CUT_BIN).
__global__ __launch_bounds__(NT) void k_pass1(
        const float* __restrict__ docs, const float* __restrict__ proto_g,
        const float* __restrict__ pn2_g, unsigned* __restrict__ hist,
        unsigned* __restrict__ cnt, uint2* __restrict__ cand, unsigned capN) {
    __shared__ float sp[SLATE*DIM];
    __shared__ float spn[SLATE];
    int t = threadIdx.x;
    if (t < SLATE*DIM) sp[t] = proto_g[t];
    if (t < SLATE) spn[t] = pn2_g[t];
    __syncthreads();
    const unsigned TOT = gridDim.x * blockDim.x;
    const unsigned gid = blockIdx.x * blockDim.x + t;
    for (unsigned base = 0; base < N_DOCS; base += 2u*TOT) {
        unsigned i0 = base + gid, i1 = base + gid + TOT;
        bool ok0 = i0 < N_DOCS, ok1 = i1 < N_DOCS;
        float a[DIM], b[DIM];
        load20(docs + (size_t)(ok0 ? i0 : 0u)*DIM, a);
        load20(docs + (size_t)(ok1 ? i1 : 0u)*DIM, b);
        float cn0 = 0.f, cn1 = 0.f;
#pragma unroll
        for (int d = 0; d < DIM; ++d) { cn0 += a[d]*a[d]; cn1 += b[d]*b[d]; }
#pragma unroll
        for (int s = 0; s < SLATE; ++s) {
            float d0 = 0.f, d1 = 0.f;
#pragma unroll
            for (int d = 0; d < DIM; ++d) {
                float p = sp[s*DIM + d];
                d0 += a[d]*p; d1 += b[d]*p;
            }
            float pn = spn[s];
            float e0 = (cn0 - 2.f*d0) + pn;
            float e1 = (cn1 - 2.f*d1) + pn;
            unsigned k0 = f2ord(e0), k1 = f2ord(e1);
            if (ok0 && (k0 >> 21) < CUT_BIN) {
                atomicAdd(&hist[s*CUT_BIN + (k0 >> 21)], 1u);
                unsigned pos = atomicAdd(&cnt[s], 1u);
                if (pos < capN) cand[(size_t)s*capN + pos] = make_uint2(k0, i0);
            }
            if (ok1 && (k1 >> 21) < CUT_BIN) {
                atomicAdd(&hist[s*CUT_BIN + (k1 >> 21)], 1u);
                unsigned pos = atomicAdd(&cnt[s], 1u);
                if (pos < capN) cand[(size_t)s*capN + pos] = make_uint2(k1, i1);
            }
        }
    }
}

// Block s: find b* (bin where cumulative count reaches KSEL), filter collected
// candidates to bin <= b*, exact-rank by (key, idx), gather docs + indices.
__global__ __launch_bounds__(256) void k_output(
        const unsigned* __restrict__ hist, const unsigned* __restrict__ cnt,
        const uint2* __restrict__ cand, const float* __restrict__ docs,
        float* __restrict__ out, unsigned capN) {
    const int CH = (CUT_BIN + 7) / 8;
    int s = blockIdx.x;
    __shared__ unsigned sh[CUT_BIN];
    __shared__ unsigned part[(CUT_BIN + 7) / 8];
    __shared__ unsigned s_bstar, s_m;
    __shared__ unsigned fk[CAPF], fi[CAPF];
    int t = threadIdx.x;
    for (int b = t; b < CUT_BIN; b += 256) sh[b] = hist[s*CUT_BIN + b];
    if (t == 0) s_m = 0;
    __syncthreads();
    for (int c = t; c < CH; c += 256) {
        unsigned acc = 0;
#pragma unroll
        for (int j = 0; j < 8; ++j) {
            int b = c*8 + j;
            if (b < CUT_BIN) acc += sh[b];
        }
        part[c] = acc;
    }
    __syncthreads();
    if (t == 0) {
        unsigned cum = 0, bstar = CUT_BIN - 1;
        bool found = false;
        for (int c = 0; c < CH && !found; ++c) {
            if (cum + part[c] >= KSEL) {
                for (int j = 0; j < 8; ++j) {
                    int b = c*8 + j;
                    if (b >= CUT_BIN) break;
                    cum += sh[b];
                    if (cum >= KSEL) { bstar = b; found = true; break; }
                }
            } else cum += part[c];
        }
        s_bstar = bstar;
    }
    __syncthreads();
    unsigned bstar = s_bstar;
    unsigned M = cnt[s]; if (M > capN) M = capN;
    for (unsigned j = t; j < M; j += 256) {
        uint2 c = cand[(size_t)s*capN + j];
        if ((c.x >> 21) <= bstar) {
            unsigned p = atomicAdd(&s_m, 1u);
            if (p < CAPF) { fk[p] = c.x; fi[p] = c.y; }
        }
    }
    __syncthreads();
    unsigned Mf = s_m < CAPF ? s_m : CAPF;
    for (unsigned j = t; j < Mf; j += 256) {
        unsigned kj = fk[j], ij = fi[j];
        unsigned r = 0;
        for (unsigned m = 0; m < Mf; ++m) {
            unsigned km = fk[m];
            r += (km < kj) || (km == kj && fi[m] < ij);
        }
        if (r < KSEL) {
            int row = s*KSEL + (int)r;
            out[(size_t)SLATE*KSEL*DIM + row] = (float)ij;  // index (exact < 2^24)
            const float* src = docs + (size_t)ij*DIM;
            float* dst = out + (size_t)row*DIM;
#pragma unroll
            for (int d = 0; d < DIM; ++d) dst[d] = src[d];
        }
    }
}

extern "C" void kernel_launch(void* const* d_in, const int* in_sizes, int n_in,
                              void* d_out, int out_size, void* d_ws, size_t ws_size,
                              hipStream_t stream) {
    const float* state = (const float*)d_in[0];
    const float* docs  = (const float*)d_in[1];
    const float* W0    = (const float*)d_in[2];
    const float* b0    = (const float*)d_in[3];
    const float* W1    = (const float*)d_in[4];
    const float* b1    = (const float*)d_in[5];
    const float* W2    = (const float*)d_in[6];
    const float* b2    = (const float*)d_in[7];
    float* out = (float*)d_out;

    char* ws = (char*)d_ws;
    float*    proto_g = (float*)(ws + 0);
    float*    pn2_g   = (float*)(ws + 512);
    unsigned* hist    = (unsigned*)(ws + 1024);
    unsigned* cnt     = (unsigned*)(ws + 32768);
    uint2*    cand    = (uint2*)(ws + 65536);

    // ws_size-adaptive per-slate candidate capacity (host-constant across calls,
    // so graph capture sees identical work every launch).
    size_t avail = ws_size > 65536 ? (ws_size - 65536) / (sizeof(uint2) * SLATE) : 0;
    unsigned capN = (unsigned)(avail < 32768 ? avail : 32768);

    k_proto<<<1, 512, 0, stream>>>(state, W0, b0, W1, b1, W2, b2,
                                   proto_g, pn2_g, hist, cnt);
    k_pass1<<<2048, NT, 0, stream>>>(docs, proto_g, pn2_g, hist, cnt, cand, capN);
    k_output<<<SLATE, 256, 0, stream>>>(hist, cnt, cand, docs, out, capN);
}

// Round 4
// 356.567 us; speedup vs baseline: 2.8405x; 2.8405x over previous
//
#include <hip/hip_runtime.h>
#include <stdint.h>

#define N_DOCS 2000000
#define DIM 20
#define SLATE 5
#define KSEL 100
#define CUT_BIN 1544   /* ord-key>>21 bin of d2 = 8.0f ; bins below => d2 < 8.0 */
#define CAPF 4096      /* per-slate filtered (bin <= b*) staged in LDS for ranking */
#define BCAP 256       /* per-block per-slate LDS candidate buffer */
#define NT 256
#define NB 1024

// ws layout (bytes):
// 0    : proto f32[128]
// 512  : pn2 f32[8]
// 1024 : cnt u32[8]
// 4096 : cand uint2[SLATE][capN]   (capN from ws_size, <= 32768)

__device__ __forceinline__ unsigned f2ord(float f) {
    unsigned u = __float_as_uint(f);
    return (u & 0x80000000u) ? ~u : (u | 0x80000000u);
}

__device__ __forceinline__ void load20(const float* __restrict__ base, float* v) {
    const float4* p = reinterpret_cast<const float4*>(base);
#pragma unroll
    for (int k = 0; k < 5; ++k) {
        float4 q = p[k];
        v[4*k+0] = q.x; v[4*k+1] = q.y; v[4*k+2] = q.z; v[4*k+3] = q.w;
    }
}

__global__ __launch_bounds__(512) void k_proto(
        const float* __restrict__ state,
        const float* __restrict__ W0, const float* __restrict__ b0,
        const float* __restrict__ W1, const float* __restrict__ b1,
        const float* __restrict__ W2, const float* __restrict__ b2,
        float* __restrict__ proto_g, float* __restrict__ pn2_g,
        unsigned* __restrict__ cnt) {
    __shared__ float s_x[DIM];
    __shared__ float s_h0[256];
    __shared__ float s_h1[512];
    __shared__ float s_p[SLATE*DIM];
    int t = threadIdx.x;
    if (t < 8) cnt[t] = 0u;         // ws re-poisoned 0xAA each launch
    if (t < DIM) s_x[t] = state[t];
    __syncthreads();
    if (t < 256) {
        float a = b0[t];
#pragma unroll
        for (int d = 0; d < DIM; ++d) a += s_x[d] * W0[d*256 + t];
        s_h0[t] = a > 0.f ? a : 0.01f*a;
    }
    __syncthreads();
    {
        float a = b1[t];
#pragma unroll 16
        for (int j = 0; j < 256; ++j) a += s_h0[j] * W1[j*512 + t];
        s_h1[t] = a > 0.f ? a : 0.01f*a;
    }
    __syncthreads();
    if (t < SLATE*DIM) {
        float a = b2[t];
#pragma unroll 16
        for (int j = 0; j < 512; ++j) a += s_h1[j] * W2[j*(SLATE*DIM) + t];
        float p = a > 0.f ? a : 0.01f*a;
        s_p[t] = p;
        proto_g[t] = p;
    }
    __syncthreads();
    if (t < SLATE) {
        float a = 0.f;
#pragma unroll
        for (int d = 0; d < DIM; ++d) { float p = s_p[t*DIM + d]; a += p*p; }
        pn2_g[t] = a;
    }
}

// Streaming pass: d2 for all (slate, doc); collect (key, idx) for d2 < 8.0
// into per-block LDS buffers; one global atomic per (block, slate) to flush.
__global__ __launch_bounds__(NT) void k_pass1(
        const float* __restrict__ docs, const float* __restrict__ proto_g,
        const float* __restrict__ pn2_g,
        unsigned* __restrict__ cnt, uint2* __restrict__ cand, unsigned capN) {
    __shared__ float sp[SLATE*DIM];
    __shared__ float spn[SLATE];
    __shared__ uint2 buf[SLATE][BCAP];
    __shared__ unsigned bcnt[SLATE];
    __shared__ unsigned bbase[SLATE];
    int t = threadIdx.x;
    if (t < SLATE*DIM) sp[t] = proto_g[t];
    if (t < SLATE) { spn[t] = pn2_g[t]; bcnt[t] = 0u; }
    __syncthreads();
    const unsigned TOT = gridDim.x * blockDim.x;
    const unsigned gid = blockIdx.x * blockDim.x + t;
    for (unsigned base = 0; base < N_DOCS; base += 2u*TOT) {
        unsigned i0 = base + gid, i1 = base + gid + TOT;
        bool ok0 = i0 < N_DOCS, ok1 = i1 < N_DOCS;
        float a[DIM], b[DIM];
        load20(docs + (size_t)(ok0 ? i0 : 0u)*DIM, a);
        load20(docs + (size_t)(ok1 ? i1 : 0u)*DIM, b);
        float cn0 = 0.f, cn1 = 0.f;
#pragma unroll
        for (int d = 0; d < DIM; ++d) { cn0 += a[d]*a[d]; cn1 += b[d]*b[d]; }
#pragma unroll
        for (int s = 0; s < SLATE; ++s) {
            float d0 = 0.f, d1 = 0.f;
#pragma unroll
            for (int d = 0; d < DIM; ++d) {
                float p = sp[s*DIM + d];
                d0 += a[d]*p; d1 += b[d]*p;
            }
            float pn = spn[s];
            unsigned k0 = f2ord((cn0 - 2.f*d0) + pn);
            unsigned k1 = f2ord((cn1 - 2.f*d1) + pn);
            if (ok0 && (k0 >> 21) < CUT_BIN) {
                unsigned pos = atomicAdd(&bcnt[s], 1u);
                if (pos < BCAP) buf[s][pos] = make_uint2(k0, i0);
                else {                                  // ~never: direct spill
                    unsigned g = atomicAdd(&cnt[s], 1u);
                    if (g < capN) cand[(size_t)s*capN + g] = make_uint2(k0, i0);
                }
            }
            if (ok1 && (k1 >> 21) < CUT_BIN) {
                unsigned pos = atomicAdd(&bcnt[s], 1u);
                if (pos < BCAP) buf[s][pos] = make_uint2(k1, i1);
                else {
                    unsigned g = atomicAdd(&cnt[s], 1u);
                    if (g < capN) cand[(size_t)s*capN + g] = make_uint2(k1, i1);
                }
            }
        }
    }
    __syncthreads();
    if (t < SLATE) {
        unsigned m = bcnt[t]; if (m > BCAP) m = BCAP;
        bcnt[t] = m;
        bbase[t] = atomicAdd(&cnt[t], m);
    }
    __syncthreads();
#pragma unroll
    for (int s = 0; s < SLATE; ++s) {
        unsigned m = bcnt[s], base = bbase[s];
        for (unsigned j = t; j < m; j += NT) {
            unsigned g = base + j;
            if (g < capN) cand[(size_t)s*capN + g] = buf[s][j];
        }
    }
}

// Block s: LDS-histogram its collected candidates, find b* (cumsum >= KSEL),
// filter to bin <= b*, exact-rank by (key, idx), gather docs + write indices.
__global__ __launch_bounds__(256) void k_output(
        const unsigned* __restrict__ cnt, const uint2* __restrict__ cand,
        const float* __restrict__ docs, float* __restrict__ out, unsigned capN) {
    const int CH = (CUT_BIN + 7) / 8;
    int s = blockIdx.x;
    __shared__ unsigned sh[CUT_BIN];
    __shared__ unsigned part[(CUT_BIN + 7) / 8];
    __shared__ unsigned s_bstar, s_m;
    __shared__ unsigned fk[CAPF], fi[CAPF];
    int t = threadIdx.x;
    for (int b = t; b < CUT_BIN; b += 256) sh[b] = 0u;
    if (t == 0) s_m = 0;
    __syncthreads();
    unsigned M = cnt[s]; if (M > capN) M = capN;
    for (unsigned j = t; j < M; j += 256) {
        unsigned key = cand[(size_t)s*capN + j].x;
        atomicAdd(&sh[key >> 21], 1u);
    }
    __syncthreads();
    for (int c = t; c < CH; c += 256) {
        unsigned acc = 0;
#pragma unroll
        for (int j = 0; j < 8; ++j) {
            int b = c*8 + j;
            if (b < CUT_BIN) acc += sh[b];
        }
        part[c] = acc;
    }
    __syncthreads();
    if (t == 0) {
        unsigned cum = 0, bstar = CUT_BIN - 1;
        bool found = false;
        for (int c = 0; c < CH && !found; ++c) {
            if (cum + part[c] >= KSEL) {
                for (int j = 0; j < 8; ++j) {
                    int b = c*8 + j;
                    if (b >= CUT_BIN) break;
                    cum += sh[b];
                    if (cum >= KSEL) { bstar = b; found = true; break; }
                }
            } else cum += part[c];
        }
        s_bstar = bstar;
    }
    __syncthreads();
    unsigned bstar = s_bstar;
    for (unsigned j = t; j < M; j += 256) {
        uint2 c = cand[(size_t)s*capN + j];
        if ((c.x >> 21) <= bstar) {
            unsigned p = atomicAdd(&s_m, 1u);
            if (p < CAPF) { fk[p] = c.x; fi[p] = c.y; }
        }
    }
    __syncthreads();
    unsigned Mf = s_m < CAPF ? s_m : CAPF;
    for (unsigned j = t; j < Mf; j += 256) {
        unsigned kj = fk[j], ij = fi[j];
        unsigned r = 0;
        for (unsigned m = 0; m < Mf; ++m) {
            unsigned km = fk[m];
            r += (km < kj) || (km == kj && fi[m] < ij);
        }
        if (r < KSEL) {
            int row = s*KSEL + (int)r;
            out[(size_t)SLATE*KSEL*DIM + row] = (float)ij;  // index (exact < 2^24)
            const float* src = docs + (size_t)ij*DIM;
            float* dst = out + (size_t)row*DIM;
#pragma unroll
            for (int d = 0; d < DIM; ++d) dst[d] = src[d];
        }
    }
}

extern "C" void kernel_launch(void* const* d_in, const int* in_sizes, int n_in,
                              void* d_out, int out_size, void* d_ws, size_t ws_size,
                              hipStream_t stream) {
    const float* state = (const float*)d_in[0];
    const float* docs  = (const float*)d_in[1];
    const float* W0    = (const float*)d_in[2];
    const float* b0    = (const float*)d_in[3];
    const float* W1    = (const float*)d_in[4];
    const float* b1    = (const float*)d_in[5];
    const float* W2    = (const float*)d_in[6];
    const float* b2    = (const float*)d_in[7];
    float* out = (float*)d_out;

    char* ws = (char*)d_ws;
    float*    proto_g = (float*)(ws + 0);
    float*    pn2_g   = (float*)(ws + 512);
    unsigned* cnt     = (unsigned*)(ws + 1024);
    uint2*    cand    = (uint2*)(ws + 4096);

    size_t avail = ws_size > 4096 ? (ws_size - 4096) / (sizeof(uint2) * SLATE) : 0;
    unsigned capN = (unsigned)(avail < 32768 ? avail : 32768);

    k_proto<<<1, 512, 0, stream>>>(state, W0, b0, W1, b1, W2, b2,
                                   proto_g, pn2_g, cnt);
    k_pass1<<<NB, NT, 0, stream>>>(docs, proto_g, pn2_g, cnt, cand, capN);
    k_output<<<SLATE, 256, 0, stream>>>(cnt, cand, docs, out, capN);
}